// Round 13
// baseline (153.964 us; speedup 1.0000x reference)
//
#include <hip/hip_runtime.h>
#include <hip/hip_bf16.h>

// GLA forward, B=4 L=2048 D=1024 H=16 DK=DV=64.
// Round 13: fuse rowsoft2+gla_recur into soft_recur (one block per (b,t) row:
// q-softmax + 6 lagged f-softmax denominators recomputed on the fly in f32,
// recurrence for all 16 heads from LDS). Merge the two cvt kernels. GEMMs
// unchanged (r11/r12-verified: QFV 872 TF, clean traffic). 6 -> 4 dispatches.

typedef __attribute__((ext_vector_type(8))) short s16x8;
typedef __attribute__((ext_vector_type(4))) float f32x4;

#define WIN 5
static const size_t NE = (size_t)8192 * 1024;

__device__ inline void gload16(const void* g, void* lds) {
  __builtin_amdgcn_global_load_lds(
      (const __attribute__((address_space(1))) unsigned int*)g,
      (__attribute__((address_space(3))) unsigned int*)lds, 16, 0, 0);
}

// ---------- QFV: 256x128, BK=64, 8 waves (4M x 2N), SINGLE buffer ----------
// (verified r11/r12: 59.3us, 872 TF, zero bank conflicts, clean traffic)
__global__ __launch_bounds__(512, 2) void gemm_sb(
    const __hip_bfloat16* __restrict__ A, const __hip_bfloat16* __restrict__ Bt,
    __hip_bfloat16* __restrict__ Obf, int K) {
  __shared__ __hip_bfloat16 sa[256 * 64];  // 32 KiB
  __shared__ __hip_bfloat16 sb[128 * 64];  // 16 KiB
  const int tid = threadIdx.x;
  const int lane = tid & 63;
  const int w = tid >> 6;
  const int wm = w >> 1, wn = w & 1;
  const int bm = blockIdx.y * 256, bn = blockIdx.x * 128;

  const int srow = tid >> 3;
  const int scol = ((tid & 7) ^ (srow & 7)) * 8;
  const int r15 = lane & 15, g = lane >> 4;
  const int rx = (r15 & 7) << 4;

  f32x4 acc[4][4] = {};
  const int NT = K / 64;
  for (int t = 0; t < NT; ++t) {
    const int bk = t * 64;
#pragma unroll
    for (int r = 0; r < 4; ++r)
      gload16(A + (size_t)(bm + r * 64 + srow) * K + bk + scol,
              &sa[r * 4096 + tid * 8]);
#pragma unroll
    for (int r = 0; r < 2; ++r)
      gload16(Bt + (size_t)(bn + r * 64 + srow) * K + bk + scol,
              &sb[r * 4096 + tid * 8]);
    __syncthreads();
    s16x8 bfr[4][2], af[4][2];
#pragma unroll
    for (int n = 0; n < 4; ++n)
#pragma unroll
      for (int ks = 0; ks < 2; ++ks)
        bfr[n][ks] = *(const s16x8*)((const char*)sb + (wn * 64 + n * 16 + r15) * 128 +
                                     ((g * 16 + ks * 64) ^ rx));
#pragma unroll
    for (int m = 0; m < 4; ++m)
#pragma unroll
      for (int ks = 0; ks < 2; ++ks)
        af[m][ks] = *(const s16x8*)((const char*)sa + (wm * 64 + m * 16 + r15) * 128 +
                                    ((g * 16 + ks * 64) ^ rx));
#pragma unroll
    for (int m = 0; m < 4; ++m)
#pragma unroll
      for (int n = 0; n < 4; ++n)
#pragma unroll
        for (int ks = 0; ks < 2; ++ks)
          acc[m][n] = __builtin_amdgcn_mfma_f32_16x16x32_bf16(
              af[m][ks], bfr[n][ks], acc[m][n], 0, 0, 0);
    __syncthreads();
  }

  const int rbase = bm + wm * 64 + (lane >> 4) * 4;
#pragma unroll
  for (int m = 0; m < 4; ++m)
#pragma unroll
    for (int n = 0; n < 4; ++n) {
      const int col = bn + wn * 64 + n * 16 + r15;
#pragma unroll
      for (int r = 0; r < 4; ++r)
        Obf[(size_t)(rbase + m * 16 + r) * 3072 + col] = __float2bfloat16(acc[m][n][r]);
    }
}

// ---------- out projection: 128x128, BK=64, 4 waves (2x2), SINGLE buffer ----
__global__ __launch_bounds__(256, 2) void gemm_sb128(
    const __hip_bfloat16* __restrict__ A, const __hip_bfloat16* __restrict__ Bt,
    float* __restrict__ C, int K) {
  __shared__ __hip_bfloat16 sa[128 * 64];
  __shared__ __hip_bfloat16 sb[128 * 64];
  const int tid = threadIdx.x;
  const int lane = tid & 63;
  const int w = tid >> 6;
  const int wm = w >> 1, wn = w & 1;
  const int bm = blockIdx.y * 128, bn = blockIdx.x * 128;

  const int srow = tid >> 3;
  const int scol = ((tid & 7) ^ (srow & 7)) * 8;
  const int r15 = lane & 15, g = lane >> 4;
  const int rx = (r15 & 7) << 4;

  f32x4 acc[4][4] = {};
  const int NT = K / 64;
  for (int t = 0; t < NT; ++t) {
    const int bk = t * 64;
#pragma unroll
    for (int r = 0; r < 4; ++r)
      gload16(A + (size_t)(bm + r * 32 + srow) * K + bk + scol,
              &sa[r * 2048 + tid * 8]);
#pragma unroll
    for (int r = 0; r < 4; ++r)
      gload16(Bt + (size_t)(bn + r * 32 + srow) * K + bk + scol,
              &sb[r * 2048 + tid * 8]);
    __syncthreads();
    s16x8 bfr[4][2], af[4][2];
#pragma unroll
    for (int n = 0; n < 4; ++n)
#pragma unroll
      for (int ks = 0; ks < 2; ++ks)
        bfr[n][ks] = *(const s16x8*)((const char*)sb + (wn * 64 + n * 16 + r15) * 128 +
                                     ((g * 16 + ks * 64) ^ rx));
#pragma unroll
    for (int m = 0; m < 4; ++m)
#pragma unroll
      for (int ks = 0; ks < 2; ++ks)
        af[m][ks] = *(const s16x8*)((const char*)sa + (wm * 64 + m * 16 + r15) * 128 +
                                    ((g * 16 + ks * 64) ^ rx));
#pragma unroll
    for (int m = 0; m < 4; ++m)
#pragma unroll
      for (int n = 0; n < 4; ++n)
#pragma unroll
        for (int ks = 0; ks < 2; ++ks)
          acc[m][n] = __builtin_amdgcn_mfma_f32_16x16x32_bf16(
              af[m][ks], bfr[n][ks], acc[m][n], 0, 0, 0);
    __syncthreads();
  }

  const int rbase = bm + wm * 64 + (lane >> 4) * 4;
#pragma unroll
  for (int m = 0; m < 4; ++m)
#pragma unroll
    for (int n = 0; n < 4; ++n) {
      const int col = bn + wn * 64 + n * 16 + r15;
#pragma unroll
      for (int r = 0; r < 4; ++r)
        C[(size_t)(rbase + m * 16 + r) * 1024 + col] = acc[m][n][r];
    }
}

// ---------- prep: blocks 0..4095 transpose W_z -> bf16; 4096..12287 cvt X ----
__global__ __launch_bounds__(256) void prep(const float* __restrict__ X,
                                            const float* __restrict__ Wq,
                                            const float* __restrict__ Wf,
                                            const float* __restrict__ Wi,
                                            const float* __restrict__ Wo,
                                            __hip_bfloat16* __restrict__ Xb,
                                            __hip_bfloat16* __restrict__ Wall) {
  const int blk = blockIdx.x;
  if (blk < 4096) {
    const int z = blk >> 10;
    const int idx = blk & 1023;
    const float* W = z == 0 ? Wq : z == 1 ? Wf : z == 2 ? Wi : Wo;
    __hip_bfloat16* Wt = Wall + (size_t)z * 1024 * 1024;
    __shared__ __hip_bfloat16 t[32][33];
    const int bx = (idx & 31) << 5, by = (idx >> 5) << 5;
    const int tx = threadIdx.x & 31, ty = threadIdx.x >> 5;
#pragma unroll
    for (int i = 0; i < 4; ++i)
      t[ty + 8 * i][tx] = __float2bfloat16(W[(size_t)(by + ty + 8 * i) * 1024 + bx + tx]);
    __syncthreads();
#pragma unroll
    for (int i = 0; i < 4; ++i)
      Wt[(size_t)(bx + ty + 8 * i) * 1024 + by + tx] = t[tx][ty + 8 * i];
  } else {
    const size_t i = ((size_t)(blk - 4096) * 256 + threadIdx.x) * 4;
    float4 v = *reinterpret_cast<const float4*>(X + i);
    __hip_bfloat16 o4[4] = {__float2bfloat16(v.x), __float2bfloat16(v.y),
                            __float2bfloat16(v.z), __float2bfloat16(v.w)};
    *reinterpret_cast<uint2*>(Xb + i) = *reinterpret_cast<uint2*>(o4);
  }
}

// ---- DPP full-wave reductions (pure VALU), result broadcast to all lanes ----
__device__ inline float wave_sum64(float x) {
  x += __int_as_float(__builtin_amdgcn_update_dpp(0, __float_as_int(x), 0xB1, 0xf, 0xf, true));
  x += __int_as_float(__builtin_amdgcn_update_dpp(0, __float_as_int(x), 0x4E, 0xf, 0xf, true));
  x += __int_as_float(__builtin_amdgcn_update_dpp(0, __float_as_int(x), 0x141, 0xf, 0xf, true));
  x += __int_as_float(__builtin_amdgcn_update_dpp(0, __float_as_int(x), 0x140, 0xf, 0xf, true));
  x += __int_as_float(__builtin_amdgcn_update_dpp(0, __float_as_int(x), 0x142, 0xa, 0xf, false));
  x += __int_as_float(__builtin_amdgcn_update_dpp(0, __float_as_int(x), 0x143, 0xc, 0xf, false));
  return __int_as_float(__builtin_amdgcn_readlane(__float_as_int(x), 63));
}
__device__ inline float wave_max64(float x) {
  x = fmaxf(x, __int_as_float(__builtin_amdgcn_update_dpp(0, __float_as_int(x), 0xB1, 0xf, 0xf, true)));
  x = fmaxf(x, __int_as_float(__builtin_amdgcn_update_dpp(0, __float_as_int(x), 0x4E, 0xf, 0xf, true)));
  x = fmaxf(x, __int_as_float(__builtin_amdgcn_update_dpp(0, __float_as_int(x), 0x141, 0xf, 0xf, true)));
  x = fmaxf(x, __int_as_float(__builtin_amdgcn_update_dpp(0, __float_as_int(x), 0x140, 0xf, 0xf, true)));
  x = fmaxf(x, __int_as_float(__builtin_amdgcn_update_dpp(0, __float_as_int(x), 0x142, 0xa, 0xf, false)));
  x = fmaxf(x, __int_as_float(__builtin_amdgcn_update_dpp(0, __float_as_int(x), 0x143, 0xc, 0xf, false)));
  return __int_as_float(__builtin_amdgcn_readlane(__float_as_int(x), 63));
}

__device__ inline float bf2f(__hip_bfloat16 b) {
  return __uint_as_float((unsigned)*reinterpret_cast<unsigned short*>(&b) << 16);
}

// ---------- fused softmax + windowed GLA recurrence ----------
// One block per (b,t) row. qfv holds LOGITS interleaved [row][q 1024|f 1024|v 1024].
// Computes q-softmax (*0.125) and e_j = softmax(f row t-j) in f32 (j=0..5,
// recomputed per block), then per-head recurrence; writes o row (bf16).
__global__ __launch_bounds__(256) void soft_recur(const __hip_bfloat16* __restrict__ qfv,
                                                  __hip_bfloat16* __restrict__ o) {
  const int row = blockIdx.x;        // b*2048 + t
  const int t = row & 2047;
  const int tid = threadIdx.x;
  const int wv = tid >> 6;
  const int lane = tid & 63;
  const int jmax = t < WIN ? t : WIN;

  __shared__ float q_lds[1024];
  __shared__ float e_lds[WIN + 1][1024];
  __shared__ float red[4][16];

  const int c = tid * 4;
  // ---- load logits (q of this row; f of rows t-j, clamped for j>t) ----
  ushort4 uq = *reinterpret_cast<const ushort4*>(qfv + (size_t)row * 3072 + c);
  float q0 = __uint_as_float((unsigned)uq.x << 16), q1 = __uint_as_float((unsigned)uq.y << 16);
  float q2 = __uint_as_float((unsigned)uq.z << 16), q3 = __uint_as_float((unsigned)uq.w << 16);
  float fv[WIN + 1][4];
#pragma unroll
  for (int j = 0; j <= WIN; ++j) {
    const int rj = (j <= jmax) ? row - j : row;
    ushort4 uf = *reinterpret_cast<const ushort4*>(qfv + (size_t)rj * 3072 + 1024 + c);
    fv[j][0] = __uint_as_float((unsigned)uf.x << 16);
    fv[j][1] = __uint_as_float((unsigned)uf.y << 16);
    fv[j][2] = __uint_as_float((unsigned)uf.z << 16);
    fv[j][3] = __uint_as_float((unsigned)uf.w << 16);
  }
  // ---- row maxes (per-wave DPP, then LDS combine) ----
  float mq = wave_max64(fmaxf(fmaxf(q0, q1), fmaxf(q2, q3)));
  float mf[WIN + 1];
#pragma unroll
  for (int j = 0; j <= WIN; ++j)
    mf[j] = wave_max64(fmaxf(fmaxf(fv[j][0], fv[j][1]), fmaxf(fv[j][2], fv[j][3])));
  if (lane == 0) {
    red[wv][0] = mq;
#pragma unroll
    for (int j = 0; j <= WIN; ++j) red[wv][1 + j] = mf[j];
  }
  __syncthreads();
  mq = fmaxf(fmaxf(red[0][0], red[1][0]), fmaxf(red[2][0], red[3][0]));
#pragma unroll
  for (int j = 0; j <= WIN; ++j)
    mf[j] = fmaxf(fmaxf(red[0][1 + j], red[1][1 + j]), fmaxf(red[2][1 + j], red[3][1 + j]));
  __syncthreads();  // red reuse below
  // ---- exps & sums ----
  float eq[4] = {expf(q0 - mq), expf(q1 - mq), expf(q2 - mq), expf(q3 - mq)};
  float ef[WIN + 1][4];
#pragma unroll
  for (int j = 0; j <= WIN; ++j)
#pragma unroll
    for (int i = 0; i < 4; ++i) ef[j][i] = expf(fv[j][i] - mf[j]);
  float sq = wave_sum64(eq[0] + eq[1] + eq[2] + eq[3]);
  float sf[WIN + 1];
#pragma unroll
  for (int j = 0; j <= WIN; ++j)
    sf[j] = wave_sum64(ef[j][0] + ef[j][1] + ef[j][2] + ef[j][3]);
  if (lane == 0) {
    red[wv][0] = sq;
#pragma unroll
    for (int j = 0; j <= WIN; ++j) red[wv][1 + j] = sf[j];
  }
  __syncthreads();
  sq = red[0][0] + red[1][0] + red[2][0] + red[3][0];
#pragma unroll
  for (int j = 0; j <= WIN; ++j)
    sf[j] = red[0][1 + j] + red[1][1 + j] + red[2][1 + j] + red[3][1 + j];
  // ---- normalize into LDS ----
  const float iq = 0.125f / sq;
  float4 qn = make_float4(eq[0] * iq, eq[1] * iq, eq[2] * iq, eq[3] * iq);
  *reinterpret_cast<float4*>(&q_lds[c]) = qn;
#pragma unroll
  for (int j = 0; j <= WIN; ++j) {
    const float is = 1.0f / sf[j];
    float4 en = make_float4(ef[j][0] * is, ef[j][1] * is, ef[j][2] * is, ef[j][3] * is);
    *reinterpret_cast<float4*>(&e_lds[j][c]) = en;
  }
  __syncthreads();
  // ---- recurrence: wave wv handles heads 4*wv .. 4*wv+3 ----
#pragma unroll
  for (int i = 0; i < 4; ++i) {
    const int h = (wv << 2) + i;
    const int col = (h << 6) + lane;
    const float qv = q_lds[col];
    float e[WIN + 1], pr[WIN + 1];
#pragma unroll
    for (int j = 0; j <= WIN; ++j) e[j] = e_lds[j][col];
    float d = 1.0f;
#pragma unroll
    for (int j = 0; j <= WIN; ++j) {
      pr[j] = (j <= jmax) ? qv * d * (1.0f - e[j]) : 0.0f;
      d *= e[j];
    }
#pragma unroll
    for (int j = 0; j <= WIN; ++j) pr[j] = wave_sum64(pr[j]);
    float acc = 0.0f;
#pragma unroll
    for (int j = 0; j <= WIN; ++j) {
      const int rj = (j <= jmax) ? row - j : row;  // pr[j]==0 masks the clamp
      acc = fmaf(pr[j], bf2f(qfv[(size_t)rj * 3072 + 2048 + col]), acc);
    }
    o[(size_t)row * 1024 + col] = __float2bfloat16(acc);
  }
}

extern "C" void kernel_launch(void* const* d_in, const int* in_sizes, int n_in,
                              void* d_out, int out_size, void* d_ws, size_t ws_size,
                              hipStream_t stream) {
  const float* X  = (const float*)d_in[0];
  const float* Wq = (const float*)d_in[1];
  const float* Wf = (const float*)d_in[2];
  const float* Wi = (const float*)d_in[3];
  const float* Wo = (const float*)d_in[4];
  float* out = (float*)d_out;

  __hip_bfloat16* qfv = (__hip_bfloat16*)d_ws;       // [8192][3072] bf16 logits/v
  __hip_bfloat16* Xb  = qfv + (size_t)8192 * 3072;   // 16 MiB
  __hip_bfloat16* Wall = Xb + NE;                    // [4][1024][1024] bf16
  __hip_bfloat16* ob  = Xb;  // alias: Xb dead after QFV GEMM

  prep<<<12288, 256, 0, stream>>>(X, Wq, Wf, Wi, Wo, Xb, Wall);
  gemm_sb<<<dim3(24, 32), 512, 0, stream>>>(Xb, Wall, qfv, 1024);
  soft_recur<<<8192, 256, 0, stream>>>(qfv, ob);
  gemm_sb128<<<dim3(8, 64), 256, 0, stream>>>(ob, Wall + (size_t)3 * 1024 * 1024,
                                              out, 1024);
}

// Round 14
// 141.322 us; speedup vs baseline: 1.0895x; 1.0895x over previous
//
#include <hip/hip_runtime.h>
#include <hip/hip_bf16.h>

// GLA forward, B=4 L=2048 D=1024 H=16 DK=DV=64.
// Round 14: revert r13 fusion (6x redundant expf recompute, 66us VALU-bound).
// r12 structure + (a) rowsoft2 with __expf/rcp (libm expf was ~25 inst each),
// (b) gla_recur rebuilt: 1 wave = 4 heads, ushort4 loads (was scalar bf16),
// 16-lane DPP butterfly reduction (4 steps, no readlane), 4x fewer waves.
// GEMMs unchanged (QFV 872 TF verified r11/r12).

typedef __attribute__((ext_vector_type(8))) short s16x8;
typedef __attribute__((ext_vector_type(4))) float f32x4;

#define WIN 5
static const size_t NE = (size_t)8192 * 1024;

__device__ inline void gload16(const void* g, void* lds) {
  __builtin_amdgcn_global_load_lds(
      (const __attribute__((address_space(1))) unsigned int*)g,
      (__attribute__((address_space(3))) unsigned int*)lds, 16, 0, 0);
}

// ---------- QFV: 256x128, BK=64, 8 waves (4M x 2N), SINGLE buffer ----------
__global__ __launch_bounds__(512, 2) void gemm_sb(
    const __hip_bfloat16* __restrict__ A, const __hip_bfloat16* __restrict__ Bt,
    __hip_bfloat16* __restrict__ Obf, int K) {
  __shared__ __hip_bfloat16 sa[256 * 64];  // 32 KiB
  __shared__ __hip_bfloat16 sb[128 * 64];  // 16 KiB
  const int tid = threadIdx.x;
  const int lane = tid & 63;
  const int w = tid >> 6;
  const int wm = w >> 1, wn = w & 1;
  const int bm = blockIdx.y * 256, bn = blockIdx.x * 128;

  const int srow = tid >> 3;
  const int scol = ((tid & 7) ^ (srow & 7)) * 8;
  const int r15 = lane & 15, g = lane >> 4;
  const int rx = (r15 & 7) << 4;

  f32x4 acc[4][4] = {};
  const int NT = K / 64;
  for (int t = 0; t < NT; ++t) {
    const int bk = t * 64;
#pragma unroll
    for (int r = 0; r < 4; ++r)
      gload16(A + (size_t)(bm + r * 64 + srow) * K + bk + scol,
              &sa[r * 4096 + tid * 8]);
#pragma unroll
    for (int r = 0; r < 2; ++r)
      gload16(Bt + (size_t)(bn + r * 64 + srow) * K + bk + scol,
              &sb[r * 4096 + tid * 8]);
    __syncthreads();
    s16x8 bfr[4][2], af[4][2];
#pragma unroll
    for (int n = 0; n < 4; ++n)
#pragma unroll
      for (int ks = 0; ks < 2; ++ks)
        bfr[n][ks] = *(const s16x8*)((const char*)sb + (wn * 64 + n * 16 + r15) * 128 +
                                     ((g * 16 + ks * 64) ^ rx));
#pragma unroll
    for (int m = 0; m < 4; ++m)
#pragma unroll
      for (int ks = 0; ks < 2; ++ks)
        af[m][ks] = *(const s16x8*)((const char*)sa + (wm * 64 + m * 16 + r15) * 128 +
                                    ((g * 16 + ks * 64) ^ rx));
#pragma unroll
    for (int m = 0; m < 4; ++m)
#pragma unroll
      for (int n = 0; n < 4; ++n)
#pragma unroll
        for (int ks = 0; ks < 2; ++ks)
          acc[m][n] = __builtin_amdgcn_mfma_f32_16x16x32_bf16(
              af[m][ks], bfr[n][ks], acc[m][n], 0, 0, 0);
    __syncthreads();
  }

  const int rbase = bm + wm * 64 + (lane >> 4) * 4;
#pragma unroll
  for (int m = 0; m < 4; ++m)
#pragma unroll
    for (int n = 0; n < 4; ++n) {
      const int col = bn + wn * 64 + n * 16 + r15;
#pragma unroll
      for (int r = 0; r < 4; ++r)
        Obf[(size_t)(rbase + m * 16 + r) * 3072 + col] = __float2bfloat16(acc[m][n][r]);
    }
}

// ---------- out projection: 128x128, BK=64, 4 waves (2x2), SINGLE buffer ----
__global__ __launch_bounds__(256, 2) void gemm_sb128(
    const __hip_bfloat16* __restrict__ A, const __hip_bfloat16* __restrict__ Bt,
    float* __restrict__ C, int K) {
  __shared__ __hip_bfloat16 sa[128 * 64];
  __shared__ __hip_bfloat16 sb[128 * 64];
  const int tid = threadIdx.x;
  const int lane = tid & 63;
  const int w = tid >> 6;
  const int wm = w >> 1, wn = w & 1;
  const int bm = blockIdx.y * 128, bn = blockIdx.x * 128;

  const int srow = tid >> 3;
  const int scol = ((tid & 7) ^ (srow & 7)) * 8;
  const int r15 = lane & 15, g = lane >> 4;
  const int rx = (r15 & 7) << 4;

  f32x4 acc[4][4] = {};
  const int NT = K / 64;
  for (int t = 0; t < NT; ++t) {
    const int bk = t * 64;
#pragma unroll
    for (int r = 0; r < 4; ++r)
      gload16(A + (size_t)(bm + r * 32 + srow) * K + bk + scol,
              &sa[r * 2048 + tid * 8]);
#pragma unroll
    for (int r = 0; r < 4; ++r)
      gload16(Bt + (size_t)(bn + r * 32 + srow) * K + bk + scol,
              &sb[r * 2048 + tid * 8]);
    __syncthreads();
    s16x8 bfr[4][2], af[4][2];
#pragma unroll
    for (int n = 0; n < 4; ++n)
#pragma unroll
      for (int ks = 0; ks < 2; ++ks)
        bfr[n][ks] = *(const s16x8*)((const char*)sb + (wn * 64 + n * 16 + r15) * 128 +
                                     ((g * 16 + ks * 64) ^ rx));
#pragma unroll
    for (int m = 0; m < 4; ++m)
#pragma unroll
      for (int ks = 0; ks < 2; ++ks)
        af[m][ks] = *(const s16x8*)((const char*)sa + (wm * 64 + m * 16 + r15) * 128 +
                                    ((g * 16 + ks * 64) ^ rx));
#pragma unroll
    for (int m = 0; m < 4; ++m)
#pragma unroll
      for (int n = 0; n < 4; ++n)
#pragma unroll
        for (int ks = 0; ks < 2; ++ks)
          acc[m][n] = __builtin_amdgcn_mfma_f32_16x16x32_bf16(
              af[m][ks], bfr[n][ks], acc[m][n], 0, 0, 0);
    __syncthreads();
  }

  const int rbase = bm + wm * 64 + (lane >> 4) * 4;
#pragma unroll
  for (int m = 0; m < 4; ++m)
#pragma unroll
    for (int n = 0; n < 4; ++n) {
      const int col = bn + wn * 64 + n * 16 + r15;
#pragma unroll
      for (int r = 0; r < 4; ++r)
        C[(size_t)(rbase + m * 16 + r) * 1024 + col] = acc[m][n][r];
    }
}

// ---------- prep: blocks 0..4095 transpose W_z -> bf16; 4096..12287 cvt X ----
__global__ __launch_bounds__(256) void prep(const float* __restrict__ X,
                                            const float* __restrict__ Wq,
                                            const float* __restrict__ Wf,
                                            const float* __restrict__ Wi,
                                            const float* __restrict__ Wo,
                                            __hip_bfloat16* __restrict__ Xb,
                                            __hip_bfloat16* __restrict__ Wall) {
  const int blk = blockIdx.x;
  if (blk < 4096) {
    const int z = blk >> 10;
    const int idx = blk & 1023;
    const float* W = z == 0 ? Wq : z == 1 ? Wf : z == 2 ? Wi : Wo;
    __hip_bfloat16* Wt = Wall + (size_t)z * 1024 * 1024;
    __shared__ __hip_bfloat16 t[32][33];
    const int bx = (idx & 31) << 5, by = (idx >> 5) << 5;
    const int tx = threadIdx.x & 31, ty = threadIdx.x >> 5;
#pragma unroll
    for (int i = 0; i < 4; ++i)
      t[ty + 8 * i][tx] = __float2bfloat16(W[(size_t)(by + ty + 8 * i) * 1024 + bx + tx]);
    __syncthreads();
#pragma unroll
    for (int i = 0; i < 4; ++i)
      Wt[(size_t)(bx + ty + 8 * i) * 1024 + by + tx] = t[tx][ty + 8 * i];
  } else {
    const size_t i = ((size_t)(blk - 4096) * 256 + threadIdx.x) * 4;
    float4 v = *reinterpret_cast<const float4*>(X + i);
    __hip_bfloat16 o4[4] = {__float2bfloat16(v.x), __float2bfloat16(v.y),
                            __float2bfloat16(v.z), __float2bfloat16(v.w)};
    *reinterpret_cast<uint2*>(Xb + i) = *reinterpret_cast<uint2*>(o4);
  }
}

// ---- DPP reductions ----
__device__ inline float wave_sum64(float x) {
  x += __int_as_float(__builtin_amdgcn_update_dpp(0, __float_as_int(x), 0xB1, 0xf, 0xf, true));
  x += __int_as_float(__builtin_amdgcn_update_dpp(0, __float_as_int(x), 0x4E, 0xf, 0xf, true));
  x += __int_as_float(__builtin_amdgcn_update_dpp(0, __float_as_int(x), 0x141, 0xf, 0xf, true));
  x += __int_as_float(__builtin_amdgcn_update_dpp(0, __float_as_int(x), 0x140, 0xf, 0xf, true));
  x += __int_as_float(__builtin_amdgcn_update_dpp(0, __float_as_int(x), 0x142, 0xa, 0xf, false));
  x += __int_as_float(__builtin_amdgcn_update_dpp(0, __float_as_int(x), 0x143, 0xc, 0xf, false));
  return __int_as_float(__builtin_amdgcn_readlane(__float_as_int(x), 63));
}
__device__ inline float wave_max64(float x) {
  x = fmaxf(x, __int_as_float(__builtin_amdgcn_update_dpp(0, __float_as_int(x), 0xB1, 0xf, 0xf, true)));
  x = fmaxf(x, __int_as_float(__builtin_amdgcn_update_dpp(0, __float_as_int(x), 0x4E, 0xf, 0xf, true)));
  x = fmaxf(x, __int_as_float(__builtin_amdgcn_update_dpp(0, __float_as_int(x), 0x141, 0xf, 0xf, true)));
  x = fmaxf(x, __int_as_float(__builtin_amdgcn_update_dpp(0, __float_as_int(x), 0x140, 0xf, 0xf, true)));
  x = fmaxf(x, __int_as_float(__builtin_amdgcn_update_dpp(0, __float_as_int(x), 0x142, 0xa, 0xf, false)));
  x = fmaxf(x, __int_as_float(__builtin_amdgcn_update_dpp(0, __float_as_int(x), 0x143, 0xc, 0xf, false)));
  return __int_as_float(__builtin_amdgcn_readlane(__float_as_int(x), 63));
}
// 16-lane butterfly sum: every lane ends with the sum of its 16-lane group.
__device__ inline float grp16_sum(float x) {
  x += __int_as_float(__builtin_amdgcn_update_dpp(0, __float_as_int(x), 0xB1, 0xf, 0xf, true));
  x += __int_as_float(__builtin_amdgcn_update_dpp(0, __float_as_int(x), 0x4E, 0xf, 0xf, true));
  x += __int_as_float(__builtin_amdgcn_update_dpp(0, __float_as_int(x), 0x141, 0xf, 0xf, true));
  x += __int_as_float(__builtin_amdgcn_update_dpp(0, __float_as_int(x), 0x140, 0xf, 0xf, true));
  return x;
}

// One block per row: q slice (softmax * 0.125) AND f slice (e = softmax(f)),
// both in place. Fast __expf + rcp (was libm expf, ~25 inst each).
__global__ __launch_bounds__(256) void rowsoft2(__hip_bfloat16* __restrict__ qfv) {
  const int row = blockIdx.x;
  const int tid = threadIdx.x;
  const int wv = tid >> 6;
  __hip_bfloat16* pq = qfv + (size_t)row * 3072;
  __hip_bfloat16* pf = pq + 1024;
  ushort4 uq = reinterpret_cast<ushort4*>(pq)[tid];
  ushort4 uf = reinterpret_cast<ushort4*>(pf)[tid];
  float q0 = __uint_as_float((unsigned)uq.x << 16), q1 = __uint_as_float((unsigned)uq.y << 16);
  float q2 = __uint_as_float((unsigned)uq.z << 16), q3 = __uint_as_float((unsigned)uq.w << 16);
  float f0 = __uint_as_float((unsigned)uf.x << 16), f1 = __uint_as_float((unsigned)uf.y << 16);
  float f2 = __uint_as_float((unsigned)uf.z << 16), f3 = __uint_as_float((unsigned)uf.w << 16);

  float mq = wave_max64(fmaxf(fmaxf(q0, q1), fmaxf(q2, q3)));
  float mf = wave_max64(fmaxf(fmaxf(f0, f1), fmaxf(f2, f3)));
  __shared__ float red[4][8];
  if ((tid & 63) == 0) { red[wv][0] = mq; red[wv][1] = mf; }
  __syncthreads();
  mq = fmaxf(fmaxf(red[0][0], red[1][0]), fmaxf(red[2][0], red[3][0]));
  mf = fmaxf(fmaxf(red[0][1], red[1][1]), fmaxf(red[2][1], red[3][1]));

  float eq0 = __expf(q0 - mq), eq1 = __expf(q1 - mq), eq2 = __expf(q2 - mq), eq3 = __expf(q3 - mq);
  float ef0 = __expf(f0 - mf), ef1 = __expf(f1 - mf), ef2 = __expf(f2 - mf), ef3 = __expf(f3 - mf);
  float sq = wave_sum64(eq0 + eq1 + eq2 + eq3);
  float sf = wave_sum64(ef0 + ef1 + ef2 + ef3);
  if ((tid & 63) == 0) { red[wv][2] = sq; red[wv][3] = sf; }
  __syncthreads();
  sq = red[0][2] + red[1][2] + red[2][2] + red[3][2];
  sf = red[0][3] + red[1][3] + red[2][3] + red[3][3];

  const float iq = 0.125f * __builtin_amdgcn_rcpf(sq);
  const float iff = __builtin_amdgcn_rcpf(sf);
  __hip_bfloat16 oq[4] = {__float2bfloat16(eq0 * iq), __float2bfloat16(eq1 * iq),
                          __float2bfloat16(eq2 * iq), __float2bfloat16(eq3 * iq)};
  __hip_bfloat16 of[4] = {__float2bfloat16(ef0 * iff), __float2bfloat16(ef1 * iff),
                          __float2bfloat16(ef2 * iff), __float2bfloat16(ef3 * iff)};
  reinterpret_cast<ushort4*>(pq)[tid] = *reinterpret_cast<ushort4*>(oq);
  reinterpret_cast<ushort4*>(pf)[tid] = *reinterpret_cast<ushort4*>(of);
}

// ---------- windowed GLA recurrence, vectorized ----------
// One wave per (row, head-group of 4). Lane l holds elements 4l..4l+3 of the
// 256-wide slice: head = hg*4 + (l>>4), k/vcol = (l&15)*4 + i. Reduction over
// k = 16-lane DPP butterfly (per-head groups align with DPP rows).
__global__ __launch_bounds__(256) void gla_recur(const __hip_bfloat16* __restrict__ qfv,
                                                 __hip_bfloat16* __restrict__ o) {
  const int w = blockIdx.x * 4 + (threadIdx.x >> 6);
  const int lane = threadIdx.x & 63;
  const int row = w >> 2;            // b*2048 + t
  const int hg = w & 3;
  const int t = row & 2047;
  const int jmax = t < WIN ? t : WIN;
  const size_t off = (size_t)hg * 256 + lane * 4;

  ushort4 uq = *reinterpret_cast<const ushort4*>(qfv + (size_t)row * 3072 + off);
  float q[4] = {__uint_as_float((unsigned)uq.x << 16), __uint_as_float((unsigned)uq.y << 16),
                __uint_as_float((unsigned)uq.z << 16), __uint_as_float((unsigned)uq.w << 16)};
  float e[WIN + 1][4], vv[WIN + 1][4];
#pragma unroll
  for (int j = 0; j <= WIN; ++j) {
    const int rj = (j <= jmax) ? row - j : row;
    ushort4 ue = *reinterpret_cast<const ushort4*>(qfv + (size_t)rj * 3072 + 1024 + off);
    ushort4 uv = *reinterpret_cast<const ushort4*>(qfv + (size_t)rj * 3072 + 2048 + off);
    e[j][0] = __uint_as_float((unsigned)ue.x << 16);
    e[j][1] = __uint_as_float((unsigned)ue.y << 16);
    e[j][2] = __uint_as_float((unsigned)ue.z << 16);
    e[j][3] = __uint_as_float((unsigned)ue.w << 16);
    vv[j][0] = __uint_as_float((unsigned)uv.x << 16);
    vv[j][1] = __uint_as_float((unsigned)uv.y << 16);
    vv[j][2] = __uint_as_float((unsigned)uv.z << 16);
    vv[j][3] = __uint_as_float((unsigned)uv.w << 16);
  }
  float d[4] = {1.0f, 1.0f, 1.0f, 1.0f};
  float pr[WIN + 1];
#pragma unroll
  for (int j = 0; j <= WIN; ++j) {
    float s = 0.0f;
#pragma unroll
    for (int i = 0; i < 4; ++i) {
      s = fmaf(q[i] * d[i], 1.0f - e[j][i], s);
      d[i] *= e[j][i];
    }
    pr[j] = (j <= jmax) ? s : 0.0f;
  }
#pragma unroll
  for (int j = 0; j <= WIN; ++j) pr[j] = grp16_sum(pr[j]);
  float acc[4] = {};
#pragma unroll
  for (int j = 0; j <= WIN; ++j)
#pragma unroll
    for (int i = 0; i < 4; ++i) acc[i] = fmaf(pr[j], vv[j][i], acc[i]);
  __hip_bfloat16 o4[4] = {__float2bfloat16(acc[0]), __float2bfloat16(acc[1]),
                          __float2bfloat16(acc[2]), __float2bfloat16(acc[3])};
  *reinterpret_cast<uint2*>(o + (size_t)row * 1024 + off) = *reinterpret_cast<uint2*>(o4);
}

extern "C" void kernel_launch(void* const* d_in, const int* in_sizes, int n_in,
                              void* d_out, int out_size, void* d_ws, size_t ws_size,
                              hipStream_t stream) {
  const float* X  = (const float*)d_in[0];
  const float* Wq = (const float*)d_in[1];
  const float* Wf = (const float*)d_in[2];
  const float* Wi = (const float*)d_in[3];
  const float* Wo = (const float*)d_in[4];
  float* out = (float*)d_out;

  __hip_bfloat16* qfv = (__hip_bfloat16*)d_ws;       // [8192][3072] bf16
  __hip_bfloat16* Xb  = qfv + (size_t)8192 * 3072;   // 16 MiB
  __hip_bfloat16* Wall = Xb + NE;                    // [4][1024][1024] bf16
  __hip_bfloat16* ob  = Xb;  // alias: Xb dead after QFV GEMM

  prep<<<12288, 256, 0, stream>>>(X, Wq, Wf, Wi, Wo, Xb, Wall);
  gemm_sb<<<dim3(24, 32), 512, 0, stream>>>(Xb, Wall, qfv, 1024);
  rowsoft2<<<8192, 256, 0, stream>>>(qfv);
  gla_recur<<<8192, 256, 0, stream>>>(qfv, ob);
  gemm_sb128<<<dim3(8, 64), 256, 0, stream>>>(ob, Wall + (size_t)3 * 1024 * 1024,
                                              out, 1024);
}